// Round 19
// baseline (60.692 us; speedup 1.0000x reference)
//
#include <hip/hip_runtime.h>
#include <math.h>

#define B_    4
#define TDEC  512
#define TENC  1024
#define H_    128
#define DT    4

typedef float f2 __attribute__((ext_vector_type(2)));

// exp(2*enc) transposed, fp16-packed: [b][gp:16][e:1024][j:8]
__device__ _Float16 g_ebp[(size_t)B_ * 16 * TENC * 8];   // 1 MB
// fp16 copy of enc in natural layout [b][e][h] (for the context phase)
__device__ _Float16 g_ench[(size_t)B_ * TENC * H_];      // 1 MB
// per (row-tile rt, g): [V4(4), then h-major ea: h0{d0..d3} .. h3{d0..d3}] = 20 f
__device__ float g_eav[(size_t)B_ * 128 * 32 * 20];      // 1.3 MB
__device__ float g_sv[1];                                // sum(V_w)

struct EAVP { float4 v4; f2 hd[8]; };
union F4 { float4 v; float f[4]; };
union H8 { float4 v; _Float16 h[8]; };
union H4 { ushort4 u4; _Float16 h[4]; };
union H2 { unsigned int u; _Float16 h[2]; };

static __device__ __forceinline__ f2 bc(float x) { f2 r = {x, x}; return r; }

// z<4: transpose enc -> fp16 exp(2*enc) planes + fp16 enc copy.  z==4: Ea+V pack.
__global__ __launch_bounds__(256) void prep_kernel(const float* __restrict__ enc,
                                                   const float* __restrict__ dec,
                                                   const float* __restrict__ Ww,
                                                   const float* __restrict__ Wb,
                                                   const float* __restrict__ Vw) {
    const int z = blockIdx.z;
    const int tx = threadIdx.x, ty = threadIdx.y;
    if (z < B_) {
        __shared__ float tile[32][33];               // [e-local][h-local]
        const int e0 = blockIdx.x * 32, h0 = blockIdx.y * 32, b = z;
        const float* ep = enc + (size_t)b * TENC * H_;
        #pragma unroll
        for (int j = 0; j < 32; j += 8) {
            const float v = ep[(size_t)(e0 + ty + j) * H_ + h0 + tx];
            tile[ty + j][tx] = v;
            g_ench[(size_t)b * TENC * H_ + (size_t)(e0 + ty + j) * H_ + h0 + tx]
                = (_Float16)v;
        }
        __syncthreads();
        // thread (tx,ty): e = e0+tx, g = h0/4+ty -> 4 fp16 (half of a gp-plane)
        const int g = (h0 >> 2) + ty, e = e0 + tx;
        const int gp = g >> 1, hs = g & 1;
        H4 o;
        // clamp below fp16 inf to avoid inf -> NaN in the rcp chain
        o.h[0] = (_Float16)fminf(__expf(2.f * tile[tx][4 * ty + 0]), 60000.f);
        o.h[1] = (_Float16)fminf(__expf(2.f * tile[tx][4 * ty + 1]), 60000.f);
        o.h[2] = (_Float16)fminf(__expf(2.f * tile[tx][4 * ty + 2]), 60000.f);
        o.h[3] = (_Float16)fminf(__expf(2.f * tile[tx][4 * ty + 3]), 60000.f);
        *(ushort4*)&g_ebp[((((size_t)b * 16 + gp) * TENC) + e) * 8 + hs * 4] = o.u4;
    } else {
        // 128 blocks x 16 rows: Ea = exp(2*(dec @ Ww^T + Wb)); pack Ea & V
        __shared__ float ds[16][H_];
        const int t = ty * 32 + tx;
        const int blk = blockIdx.y * 32 + blockIdx.x;      // 0..127
        const int R0 = blk * 16;
        #pragma unroll
        for (int i = 0; i < 8; ++i) {
            const int f = t + 256 * i;
            ds[f >> 7][f & 127] = dec[(size_t)R0 * H_ + f];
        }
        __syncthreads();
        const int k = t & 127, dd = t >> 7;
        const float* wr = Ww + (size_t)k * H_;
        float s[8];
        #pragma unroll
        for (int j = 0; j < 8; ++j) s[j] = 0.f;
        for (int h = 0; h < H_; h += 4) {
            const float4 w4 = *(const float4*)(wr + h);
            #pragma unroll
            for (int j = 0; j < 8; ++j) {
                const float4 d4 = *(const float4*)&ds[dd + 2 * j][h];
                s[j] = fmaf(w4.x, d4.x, s[j]);
                s[j] = fmaf(w4.y, d4.y, s[j]);
                s[j] = fmaf(w4.z, d4.z, s[j]);
                s[j] = fmaf(w4.w, d4.w, s[j]);
            }
        }
        const float wb = Wb[k], vw = Vw[k];
        const int g = k >> 2, jj = k & 3;
        #pragma unroll
        for (int j = 0; j < 8; ++j) {
            const int rl = dd + 2 * j;          // row within 16-row block
            const int R = R0 + rl;
            const float ea = __expf(2.f * (s[j] + wb));
            // h-major, d-minor: enables packed d-pair math in the fused kernel
            g_eav[((size_t)(R >> 2) * 32 + g) * 20 + 4 + jj * 4 + (R & 3)] = ea;
        }
        if (dd == 0) {
            #pragma unroll
            for (int r = 0; r < 4; ++r)
                g_eav[((size_t)((R0 >> 2) + r) * 32 + g) * 20 + jj] = vw;
        }
        if (blk == 0) {
            __shared__ float svp[2];
            if (t < 128) {
                float x = vw;
                #pragma unroll
                for (int off = 32; off; off >>= 1) x += __shfl_xor(x, off);
                if ((t & 63) == 0) svp[t >> 6] = x;
            }
            __syncthreads();
            if (t == 0) g_sv[0] = svp[0] + svp[1];
        }
    }
}

// Packed 4-h fraction combine over a d-pair: one VOP3P op per step, 2 scalar rcp.
__device__ __forceinline__ f2 term4p(f2 p0, f2 p1, f2 p2, f2 p3,
                                     const float4 v4, f2 acc) {
    const f2 q01 = p0 * p1, q23 = p2 * p3;
    const f2 a   = __builtin_elementwise_fma(bc(v4.y), p0, bc(v4.x) * p1);
    const f2 bq  = __builtin_elementwise_fma(bc(v4.w), p2, bc(v4.z) * p3);
    const f2 num = __builtin_elementwise_fma(bq, q01, a * q23);
    const f2 den = q01 * q23;
    f2 r;
    r.x = __builtin_amdgcn_rcpf(den.x);
    r.y = __builtin_amdgcn_rcpf(den.y);
    return __builtin_elementwise_fma(num, r, acc);
}

// Both d-pairs for one g (4 h-planes), te given as 4 scalars.
#define DALLP(S, t0, t1, t2, t3) do {                                          \
    const f2 one2 = {1.f, 1.f};                                                \
    f2 pA0 = __builtin_elementwise_fma(S.hd[0], bc(t0), one2);                 \
    f2 pB0 = __builtin_elementwise_fma(S.hd[1], bc(t0), one2);                 \
    f2 pA1 = __builtin_elementwise_fma(S.hd[2], bc(t1), one2);                 \
    f2 pB1 = __builtin_elementwise_fma(S.hd[3], bc(t1), one2);                 \
    f2 pA2 = __builtin_elementwise_fma(S.hd[4], bc(t2), one2);                 \
    f2 pB2 = __builtin_elementwise_fma(S.hd[5], bc(t2), one2);                 \
    f2 pA3 = __builtin_elementwise_fma(S.hd[6], bc(t3), one2);                 \
    f2 pB3 = __builtin_elementwise_fma(S.hd[7], bc(t3), one2);                 \
    acc01 = term4p(pA0, pA1, pA2, pA3, S.v4, acc01);                           \
    acc23 = term4p(pB0, pB1, pB2, pB3, S.v4, acc23);                           \
} while (0)

// Fused: score + softmax(sum-only) + context + write.  Block = 1 row-tile
// (4 rows), 1024 threads (thread owns 1 e); grid 512, XCD-swizzled.
// Phase 1: wave-ROTATED gp order — wave w starts at gp=w, so the 16 waves'
// load/compute windows interleave instead of convoying (stall de-alignment).
__global__ __launch_bounds__(1024, 8) void fused_kernel(float* __restrict__ out) {
    __shared__ float sc[DT][TENC];          // p = exp(score)      (16 KB)
    __shared__ f2 part[16][DT][64];         // context partials    (32 KB)
    __shared__ float wsum[16][DT];
    __shared__ float rsum[DT];

    const int t = threadIdx.x;
    const int w = t >> 6;
    // XCD-locality swizzle: XCD x (= bid%8) gets contiguous row-tiles
    const int bid = blockIdx.x;
    const int rt = (bid & 7) * 64 + (bid >> 3);
    const int b = rt >> 7;
    const int R0 = rt * DT;
    const EAVP* epk = (const EAVP*)g_eav + (size_t)rt * 32;
    const _Float16* teb = g_ebp + (size_t)b * 16 * TENC * 8 + t * 8;
    const float sv = g_sv[0];

    // --- Phase 1: scores; 16 load events, packed math; wave-rotated order ---
    f2 acc01 = {0.f, 0.f}, acc23 = {0.f, 0.f};

    for (int gpi = 0; gpi < 16; ++gpi) {
        const int gp = (gpi + w) & 15;      // per-wave rotation (bijective)
        H8 r;
        r.v = *(const float4*)(teb + (size_t)gp * (TENC * 8));
        const float t0 = (float)r.h[0], t1 = (float)r.h[1];
        const float t2 = (float)r.h[2], t3 = (float)r.h[3];
        const float t4 = (float)r.h[4], t5 = (float)r.h[5];
        const float t6 = (float)r.h[6], t7 = (float)r.h[7];
        const EAVP A  = epk[2 * gp];
        const EAVP Bv = epk[2 * gp + 1];
        DALLP(A, t0, t1, t2, t3);
        DALLP(Bv, t4, t5, t6, t7);
    }

    // --- Phase 2: p = exp(score); stash + per-wave partial sums ---
    const float q0 = __expf(fmaf(-2.f, acc01.x, sv));
    const float q1 = __expf(fmaf(-2.f, acc01.y, sv));
    const float q2 = __expf(fmaf(-2.f, acc23.x, sv));
    const float q3 = __expf(fmaf(-2.f, acc23.y, sv));
    sc[0][t] = q0; sc[1][t] = q1; sc[2][t] = q2; sc[3][t] = q3;

    float s0 = q0, s1 = q1, s2 = q2, s3 = q3;
    #pragma unroll
    for (int off = 32; off; off >>= 1) {
        s0 += __shfl_xor(s0, off);
        s1 += __shfl_xor(s1, off);
        s2 += __shfl_xor(s2, off);
        s3 += __shfl_xor(s3, off);
    }
    {
        const int lane = t & 63;
        if (lane == 0) { wsum[w][0] = s0; wsum[w][1] = s1; wsum[w][2] = s2; wsum[w][3] = s3; }
    }
    __syncthreads();
    if (t < 64) {                            // lane = w'*4 + d
        float x = wsum[t >> 2][t & 3];
        #pragma unroll
        for (int off = 4; off < 64; off <<= 1) x += __shfl_xor(x, off);
        if (t < 4) rsum[t] = x;
    }

    // --- Phase 3: context partials from fp16 enc; packed (x,y) h-pair math ---
    {
        const int q = t >> 6, h2 = t & 63;
        const _Float16* eb = g_ench + (size_t)b * TENC * H_ + 2 * h2;
        f2 a0 = {0.f, 0.f}, a1 = {0.f, 0.f}, a2 = {0.f, 0.f}, a3 = {0.f, 0.f};
        const int e0 = q * 64;
        for (int e = e0; e < e0 + 64; e += 4) {
            F4 u0, u1, u2, u3;
            u0.v = *(const float4*)&sc[0][e];
            u1.v = *(const float4*)&sc[1][e];
            u2.v = *(const float4*)&sc[2][e];
            u3.v = *(const float4*)&sc[3][e];
            #pragma unroll
            for (int j = 0; j < 4; ++j) {
                H2 hv; hv.u = *(const unsigned int*)(eb + (size_t)(e + j) * H_);
                f2 ev; ev.x = (float)hv.h[0]; ev.y = (float)hv.h[1];
                a0 = __builtin_elementwise_fma(bc(u0.f[j]), ev, a0);
                a1 = __builtin_elementwise_fma(bc(u1.f[j]), ev, a1);
                a2 = __builtin_elementwise_fma(bc(u2.f[j]), ev, a2);
                a3 = __builtin_elementwise_fma(bc(u3.f[j]), ev, a3);
            }
        }
        part[q][0][h2] = a0; part[q][1][h2] = a1;
        part[q][2][h2] = a2; part[q][3][h2] = a3;
    }
    __syncthreads();

    // --- Phase 4: merge 16 slices, divide, write ---
    if (t < 256) {
        const int d = t >> 6, h2 = t & 63;
        f2 s = {0.f, 0.f};
        #pragma unroll
        for (int q = 0; q < 16; ++q) s += part[q][d][h2];
        const float rinv = __builtin_amdgcn_rcpf(rsum[d]);
        s *= bc(rinv);
        *(f2*)(out + (size_t)(R0 + d) * H_ + 2 * h2) = s;
    }
}

extern "C" void kernel_launch(void* const* d_in, const int* in_sizes, int n_in,
                              void* d_out, int out_size, void* d_ws, size_t ws_size,
                              hipStream_t stream) {
    const float* dec = (const float*)d_in[0];
    const float* enc = (const float*)d_in[1];
    const float* Ww  = (const float*)d_in[2];
    const float* Wb  = (const float*)d_in[3];
    const float* Vw  = (const float*)d_in[4];
    float* out = (float*)d_out;

    prep_kernel<<<dim3(TENC / 32, H_ / 32, B_ + 1), dim3(32, 8), 0, stream>>>(
        enc, dec, Ww, Wb, Vw);
    fused_kernel<<<dim3(B_ * 128), dim3(1024), 0, stream>>>(out);
}

// Round 20
// 41.627 us; speedup vs baseline: 1.4580x; 1.4580x over previous
//
#include <hip/hip_runtime.h>
#include <math.h>

#define B_    4
#define TDEC  512
#define TENC  1024
#define H_    128
#define DT    4

typedef float f2 __attribute__((ext_vector_type(2)));
typedef float f32x4v __attribute__((ext_vector_type(4)));
typedef _Float16 h8v __attribute__((ext_vector_type(8)));

// exp(2*enc) transposed, fp16-packed: [b][gp:16][e:1024][j:8]
__device__ _Float16 g_ebp[(size_t)B_ * 16 * TENC * 8];     // 1 MB
// enc in MFMA B-fragment order: [b][n:8][kk:32][lane:64][j:8] fp16
__device__ _Float16 g_encB[(size_t)B_ * 8 * 32 * 64 * 8];  // 1 MB
// per (row-tile rt, g): [V4(4), h-major ea d-pairs] = 20 f
__device__ float g_eav[(size_t)B_ * 128 * 32 * 20];        // 1.3 MB
__device__ float g_sv[1];                                  // sum(V_w)

struct EAVP { float4 v4; f2 hd[8]; };
union H8u { float4 v; _Float16 h[8]; h8v hv; };
union H4u { ushort4 u4; _Float16 h[4]; };

static __device__ __forceinline__ f2 bc(float x) { f2 r = {x, x}; return r; }

// z<4: transpose enc -> g_ebp (fp16 exp planes) + g_encB (B-fragments).
// z==4: Ea rows + V pack + SV.
__global__ __launch_bounds__(256) void prep_kernel(const float* __restrict__ enc,
                                                   const float* __restrict__ dec,
                                                   const float* __restrict__ Ww,
                                                   const float* __restrict__ Wb,
                                                   const float* __restrict__ Vw) {
    const int z = blockIdx.z;
    const int tx = threadIdx.x, ty = threadIdx.y;
    if (z < B_) {
        __shared__ float tile[32][33];               // [e-local][h-local]
        const int e0 = blockIdx.x * 32, h0 = blockIdx.y * 32, b = z;
        const float* ep = enc + (size_t)b * TENC * H_;
        #pragma unroll
        for (int j = 0; j < 32; j += 8)
            tile[ty + j][tx] = ep[(size_t)(e0 + ty + j) * H_ + h0 + tx];
        __syncthreads();
        // te planes: thread (tx,ty): e = e0+tx, g = h0/4+ty
        const int g = (h0 >> 2) + ty, e = e0 + tx;
        const int gp = g >> 1, hs = g & 1;
        H4u o;
        o.h[0] = (_Float16)fminf(__expf(2.f * tile[tx][4 * ty + 0]), 60000.f);
        o.h[1] = (_Float16)fminf(__expf(2.f * tile[tx][4 * ty + 1]), 60000.f);
        o.h[2] = (_Float16)fminf(__expf(2.f * tile[tx][4 * ty + 2]), 60000.f);
        o.h[3] = (_Float16)fminf(__expf(2.f * tile[tx][4 * ty + 3]), 60000.f);
        *(ushort4*)&g_ebp[((((size_t)b * 16 + gp) * TENC) + e) * 8 + hs * 4] = o.u4;
        // enc B-fragments: elem j of lane l at (n,kk) = enc[kk*32+lg*8+j][n*16+hl]
        const int kk = e >> 5, lg = (e >> 3) & 3, jj = e & 7;
        #pragma unroll
        for (int k = 0; k < 4; ++k) {
            const int h = h0 + 4 * ty + k;
            const int n = h >> 4, hl = h & 15;
            g_encB[((((size_t)b * 8 + n) * 32 + kk) * 64 + (lg * 16 + hl)) * 8 + jj]
                = (_Float16)tile[tx][4 * ty + k];
        }
    } else {
        // 128 blocks x 16 rows: Ea = exp(2*(dec @ Ww^T + Wb)); pack Ea & V
        __shared__ float ds[16][H_];
        const int t = ty * 32 + tx;
        const int blk = blockIdx.y * 32 + blockIdx.x;      // 0..127
        const int R0 = blk * 16;
        #pragma unroll
        for (int i = 0; i < 8; ++i) {
            const int f = t + 256 * i;
            ds[f >> 7][f & 127] = dec[(size_t)R0 * H_ + f];
        }
        __syncthreads();
        const int k = t & 127, dd = t >> 7;
        const float* wr = Ww + (size_t)k * H_;
        float s[8];
        #pragma unroll
        for (int j = 0; j < 8; ++j) s[j] = 0.f;
        for (int h = 0; h < H_; h += 4) {
            const float4 w4 = *(const float4*)(wr + h);
            #pragma unroll
            for (int j = 0; j < 8; ++j) {
                const float4 d4 = *(const float4*)&ds[dd + 2 * j][h];
                s[j] = fmaf(w4.x, d4.x, s[j]);
                s[j] = fmaf(w4.y, d4.y, s[j]);
                s[j] = fmaf(w4.z, d4.z, s[j]);
                s[j] = fmaf(w4.w, d4.w, s[j]);
            }
        }
        const float wb = Wb[k], vw = Vw[k];
        const int g = k >> 2, jj = k & 3;
        #pragma unroll
        for (int j = 0; j < 8; ++j) {
            const int rl = dd + 2 * j;
            const int R = R0 + rl;
            const float ea = __expf(2.f * (s[j] + wb));
            // h-major, d-minor (packed d-pair math)
            g_eav[((size_t)(R >> 2) * 32 + g) * 20 + 4 + jj * 4 + (R & 3)] = ea;
        }
        if (dd == 0) {
            #pragma unroll
            for (int r = 0; r < 4; ++r)
                g_eav[((size_t)((R0 >> 2) + r) * 32 + g) * 20 + jj] = vw;
        }
        if (blk == 0) {
            __shared__ float svp[2];
            if (t < 128) {
                float x = vw;
                #pragma unroll
                for (int off = 32; off; off >>= 1) x += __shfl_xor(x, off);
                if ((t & 63) == 0) svp[t >> 6] = x;
            }
            __syncthreads();
            if (t == 0) g_sv[0] = svp[0] + svp[1];
        }
    }
}

// Packed 4-h fraction combine over a d-pair; one VOP3P op per step, 2 rcp.
__device__ __forceinline__ f2 term4p(f2 p0, f2 p1, f2 p2, f2 p3,
                                     const float4 v4, f2 acc) {
    const f2 q01 = p0 * p1, q23 = p2 * p3;
    const f2 a   = __builtin_elementwise_fma(bc(v4.y), p0, bc(v4.x) * p1);
    const f2 bq  = __builtin_elementwise_fma(bc(v4.w), p2, bc(v4.z) * p3);
    const f2 num = __builtin_elementwise_fma(bq, q01, a * q23);
    const f2 den = q01 * q23;
    f2 r;
    r.x = __builtin_amdgcn_rcpf(den.x);
    r.y = __builtin_amdgcn_rcpf(den.y);
    return __builtin_elementwise_fma(num, r, acc);
}

#define DALLP(S, t0, t1, t2, t3) do {                                          \
    const f2 one2 = {1.f, 1.f};                                                \
    f2 pA0 = __builtin_elementwise_fma(S.hd[0], bc(t0), one2);                 \
    f2 pB0 = __builtin_elementwise_fma(S.hd[1], bc(t0), one2);                 \
    f2 pA1 = __builtin_elementwise_fma(S.hd[2], bc(t1), one2);                 \
    f2 pB1 = __builtin_elementwise_fma(S.hd[3], bc(t1), one2);                 \
    f2 pA2 = __builtin_elementwise_fma(S.hd[4], bc(t2), one2);                 \
    f2 pB2 = __builtin_elementwise_fma(S.hd[5], bc(t2), one2);                 \
    f2 pA3 = __builtin_elementwise_fma(S.hd[6], bc(t3), one2);                 \
    f2 pB3 = __builtin_elementwise_fma(S.hd[7], bc(t3), one2);                 \
    acc01 = term4p(pA0, pA1, pA2, pA3, S.v4, acc01);                           \
    acc23 = term4p(pB0, pB1, pB2, pB3, S.v4, acc23);                           \
} while (0)

// Fused: score + softmax(max+sum) + MFMA context + write.  Block = 1 row-tile
// (4 rows), 1024 threads; grid 512, XCD-swizzled.  Context: P[16pad x 1024]
// (fp16, LDS swizzled) x enc B-fragments (global, pre-laid) on matrix cores.
__global__ __launch_bounds__(1024, 8) void fused_kernel(float* __restrict__ out) {
    __shared__ __align__(16) _Float16 sc_h[16 * TENC];   // 32 KB, rows 4-15 zero
    __shared__ float wred[16][4];
    __shared__ float rmax4[4], rsum4[4];
    __shared__ __align__(16) float cx[8][16][4];         // 2 KB k-half exchange

    const int t = threadIdx.x;
    const int w = t >> 6, lane = t & 63;
    const int bid = blockIdx.x;
    const int rt = (bid & 7) * 64 + (bid >> 3);          // XCD swizzle
    const int b = rt >> 7;
    const int R0 = rt * DT;
    const EAVP* epk = (const EAVP*)g_eav + (size_t)rt * 32;
    const _Float16* teb = g_ebp + (size_t)b * 16 * TENC * 8 + t * 8;
    const float sv = g_sv[0];

    // zero-pad A rows 4..15 (24 KB, coalesced)
    {
        int* z = (int*)sc_h + 2048;
        #pragma unroll
        for (int i = 0; i < 6; ++i) z[t + 1024 * i] = 0;
    }

    // --- Phase 1: scores (r16-exact) ---
    f2 acc01 = {0.f, 0.f}, acc23 = {0.f, 0.f};
    for (int gp = 0; gp < 16; ++gp) {
        H8u r;
        r.v = *(const float4*)(teb + (size_t)gp * (TENC * 8));
        const float t0 = (float)r.h[0], t1 = (float)r.h[1];
        const float t2 = (float)r.h[2], t3 = (float)r.h[3];
        const float t4 = (float)r.h[4], t5 = (float)r.h[5];
        const float t6 = (float)r.h[6], t7 = (float)r.h[7];
        const EAVP A  = epk[2 * gp];
        const EAVP Bv = epk[2 * gp + 1];
        DALLP(A, t0, t1, t2, t3);
        DALLP(Bv, t4, t5, t6, t7);
    }

    // --- Phase 2: block max -> p = exp(s - max) -> fp16 P + block sum ---
    const float s0 = fmaf(-2.f, acc01.x, sv);
    const float s1 = fmaf(-2.f, acc01.y, sv);
    const float s2 = fmaf(-2.f, acc23.x, sv);
    const float s3 = fmaf(-2.f, acc23.y, sv);
    {
        float m0 = s0, m1 = s1, m2 = s2, m3 = s3;
        #pragma unroll
        for (int off = 32; off; off >>= 1) {
            m0 = fmaxf(m0, __shfl_xor(m0, off));
            m1 = fmaxf(m1, __shfl_xor(m1, off));
            m2 = fmaxf(m2, __shfl_xor(m2, off));
            m3 = fmaxf(m3, __shfl_xor(m3, off));
        }
        if (lane == 0) { wred[w][0] = m0; wred[w][1] = m1; wred[w][2] = m2; wred[w][3] = m3; }
    }
    __syncthreads();
    if (t < 64) {
        float x = wred[t >> 2][t & 3];
        #pragma unroll
        for (int off = 4; off < 64; off <<= 1) x = fmaxf(x, __shfl_xor(x, off));
        if (t < 4) rmax4[t] = x;
    }
    __syncthreads();
    {
        const _Float16 h0 = (_Float16)__expf(s0 - rmax4[0]);
        const _Float16 h1 = (_Float16)__expf(s1 - rmax4[1]);
        const _Float16 h2 = (_Float16)__expf(s2 - rmax4[2]);
        const _Float16 h3 = (_Float16)__expf(s3 - rmax4[3]);
        // swizzled stores: byte = row*2048 + e*2, ^ (row<<4)
        *(_Float16*)((char*)sc_h + ((0 * 2048 + t * 2) ^ 0))  = h0;
        *(_Float16*)((char*)sc_h + ((1 * 2048 + t * 2) ^ 16)) = h1;
        *(_Float16*)((char*)sc_h + ((2 * 2048 + t * 2) ^ 32)) = h2;
        *(_Float16*)((char*)sc_h + ((3 * 2048 + t * 2) ^ 48)) = h3;
        float f0 = (float)h0, f1 = (float)h1, f2s = (float)h2, f3 = (float)h3;
        #pragma unroll
        for (int off = 32; off; off >>= 1) {
            f0 += __shfl_xor(f0, off);
            f1 += __shfl_xor(f1, off);
            f2s += __shfl_xor(f2s, off);
            f3 += __shfl_xor(f3, off);
        }
        if (lane == 0) { wred[w][0] = f0; wred[w][1] = f1; wred[w][2] = f2s; wred[w][3] = f3; }
    }
    __syncthreads();
    if (t < 64) {
        float x = wred[t >> 2][t & 3];
        #pragma unroll
        for (int off = 4; off < 64; off <<= 1) x += __shfl_xor(x, off);
        if (t < 4) rsum4[t] = x;
    }

    // --- Phase 3: ctx = P x enc via MFMA.  Wave w: n-tile w&7, k-half w>>3 ---
    {
        const int n = w & 7, kh = w >> 3;
        const int row = lane & 15, lg = lane >> 4;
        f32x4v acc = {0.f, 0.f, 0.f, 0.f};
        const int ab = row * 2048 + kh * 1024 + lg * 16;   // byte base in sc_h
        const int swz = (row & 7) << 4;
        const char* bptr = (const char*)g_encB
            + ((((size_t)b * 8 + n) * 32 + kh * 16) * 64 + lane) * 16;
        #pragma unroll
        for (int ks = 0; ks < 16; ++ks) {
            H8u au, bu;
            au.v = *(const float4*)((const char*)sc_h + ((ab + ks * 64) ^ swz));
            bu.v = *(const float4*)(bptr + ks * 1024);
            acc = __builtin_amdgcn_mfma_f32_16x16x32_f16(au.hv, bu.hv, acc, 0, 0, 0);
        }
        // C layout (m89): col = lane&15, row = (lane>>4)*4 + reg -> lanes 0-15
        // hold rows 0-3 in regs 0-3.
        if (w >= 8 && lane < 16) *(f32x4v*)&cx[n][lane][0] = acc;
        __syncthreads();
        if (w < 8 && lane < 16) {
            const f32x4v c2 = *(const f32x4v*)&cx[n][lane][0];
            float* op = out + (size_t)R0 * H_ + n * 16 + lane;
            op[0 * H_] = (acc.x + c2.x) * __builtin_amdgcn_rcpf(rsum4[0]);
            op[1 * H_] = (acc.y + c2.y) * __builtin_amdgcn_rcpf(rsum4[1]);
            op[2 * H_] = (acc.z + c2.z) * __builtin_amdgcn_rcpf(rsum4[2]);
            op[3 * H_] = (acc.w + c2.w) * __builtin_amdgcn_rcpf(rsum4[3]);
        }
    }
}

extern "C" void kernel_launch(void* const* d_in, const int* in_sizes, int n_in,
                              void* d_out, int out_size, void* d_ws, size_t ws_size,
                              hipStream_t stream) {
    const float* dec = (const float*)d_in[0];
    const float* enc = (const float*)d_in[1];
    const float* Ww  = (const float*)d_in[2];
    const float* Wb  = (const float*)d_in[3];
    const float* Vw  = (const float*)d_in[4];
    float* out = (float*)d_out;

    prep_kernel<<<dim3(TENC / 32, H_ / 32, B_ + 1), dim3(32, 8), 0, stream>>>(
        enc, dec, Ww, Wb, Vw);
    fused_kernel<<<dim3(B_ * 128), dim3(1024), 0, stream>>>(out);
}